// Round 12
// baseline (1880.386 us; speedup 1.0000x reference)
//
#include <hip/hip_runtime.h>
#include <hip/hip_bf16.h>
#include <math.h>

#define NPART 16  // s-blocks of 256: 64x16 = 1024 blocks

typedef __attribute__((ext_vector_type(8))) short bf16x8;  // MFMA A/B frag (4 VGPR)
typedef __attribute__((ext_vector_type(4))) float f32x4;   // MFMA C/D frag

static __device__ inline ushort f2bf(float x) {
  __hip_bfloat16 h = __float2bfloat16(x);
  return *reinterpret_cast<ushort*>(&h);
}

// ---------------------------------------------------------------------------
__global__ __launch_bounds__(256) void cast_bf16_kernel(
    const float* __restrict__ in, ushort* __restrict__ out, size_t n4) {
  size_t i = (size_t)blockIdx.x * blockDim.x + threadIdx.x;
  size_t stride = (size_t)gridDim.x * blockDim.x;
  for (; i < n4; i += stride) {
    float4 v = ((const float4*)in)[i];
    ushort4 u;
    u.x = f2bf(v.x); u.y = f2bf(v.y); u.z = f2bf(v.z); u.w = f2bf(v.w);
    ((ushort4*)out)[i] = u;
  }
}

// ---------------------------------------------------------------------------
__global__ __launch_bounds__(256) void transpose_cast_kernel(
    const float* __restrict__ W, ushort* __restrict__ Wt, int K, int D) {
  __shared__ float t[64][65];
  const int k0 = blockIdx.x * 64, d0 = blockIdx.y * 64;
  const int r = threadIdx.x >> 6, c = threadIdx.x & 63;
#pragma unroll
  for (int i = 0; i < 16; i++)
    t[r + i * 4][c] = W[(size_t)(k0 + r + i * 4) * D + d0 + c];
  __syncthreads();
#pragma unroll
  for (int i = 0; i < 16; i++)
    Wt[(size_t)(d0 + r + i * 4) * K + k0 + c] = f2bf(t[c][r + i * 4]);
}

// ---------------------------------------------------------------------------
__global__ __launch_bounds__(256) void encode_mfma_kernel(
    const ushort* __restrict__ Xb, const ushort* __restrict__ Wt,
    const float* __restrict__ bias, float* __restrict__ emb,
    int K, int D) {
  const int tid = threadIdx.x;
  const int wave = tid >> 6, lane = tid & 63;
  const int fr = lane & 15, kg = lane >> 4;
  const long row0 = (long)blockIdx.x * 64, col0 = (long)blockIdx.y * 64;

  f32x4 acc[4];
#pragma unroll
  for (int c = 0; c < 4; c++) acc[c] = (f32x4){0.f, 0.f, 0.f, 0.f};

  const ushort* xrow = Xb + (row0 + wave * 16 + fr) * (size_t)K;
  const int nt = K / 32;
  for (int t = 0; t < nt; t++) {
    bf16x8 af = *(const bf16x8*)(xrow + t * 32 + kg * 8);
#pragma unroll
    for (int c = 0; c < 4; c++) {
      const ushort* wrow = Wt + (col0 + c * 16 + fr) * (size_t)K;
      bf16x8 bf = *(const bf16x8*)(wrow + t * 32 + kg * 8);
      acc[c] = __builtin_amdgcn_mfma_f32_16x16x32_bf16(af, bf, acc[c], 0, 0, 0);
    }
  }
#pragma unroll
  for (int c = 0; c < 4; c++) {
    float bl = bias[col0 + c * 16 + fr];
#pragma unroll
    for (int r = 0; r < 4; r++)
      emb[(row0 + wave * 16 + kg * 4 + r) * (size_t)D + col0 + c * 16 + fr] =
          acc[c][r] + bl;
  }
}

// ---------------------------------------------------------------------------
__global__ __launch_bounds__(256) void norm_bf16_kernel(
    const float* __restrict__ in, ushort* __restrict__ outb, int nrows, int D) {
  int row = (int)((blockIdx.x * blockDim.x + threadIdx.x) >> 6);
  int lane = threadIdx.x & 63;
  if (row >= nrows) return;
  const float4* p = (const float4*)(in + (size_t)row * D);
  float4 v0 = p[lane];
  float4 v1 = p[lane + 64];
  float ss = v0.x * v0.x + v0.y * v0.y + v0.z * v0.z + v0.w * v0.w
           + v1.x * v1.x + v1.y * v1.y + v1.z * v1.z + v1.w * v1.w;
#pragma unroll
  for (int off = 32; off > 0; off >>= 1) ss += __shfl_xor(ss, off);
  float inv = 1.0f / fmaxf(sqrtf(ss), 1e-12f);
  ushort4 u0, u1;
  u0.x = f2bf(v0.x * inv); u0.y = f2bf(v0.y * inv);
  u0.z = f2bf(v0.z * inv); u0.w = f2bf(v0.w * inv);
  u1.x = f2bf(v1.x * inv); u1.y = f2bf(v1.y * inv);
  u1.z = f2bf(v1.z * inv); u1.w = f2bf(v1.w * inv);
  ushort* o = outb + (size_t)row * D;
  *(ushort4*)(o + 4 * lane) = u0;
  *(ushort4*)(o + 256 + 4 * lane) = u1;
}

// ---------------------------------------------------------------------------
// REAL attention kernel — byte-identical structure to round 10/11 (passes).
// ---------------------------------------------------------------------------
#define STAGE_BODY(kt, pb)                                                    \
  {                                                                           \
    _Pragma("unroll")                                                         \
    for (int i_ = 0; i_ < 3; i_++) {                                          \
      const int seg_ = wave * 3 + i_;                                         \
      const ushort* src_ = (seg_ < 8)                                         \
          ? Qb + (q0 + seg_ * 16 + fr) * (size_t)D + (kt) * 32 + kg * 8       \
          : Sb + (s0 + (seg_ - 8) * 16 + fr) * (size_t)D + (kt) * 32 + kg * 8;\
      __builtin_amdgcn_global_load_lds(                                       \
          (const __attribute__((address_space(1))) void*)src_,                \
          (__attribute__((address_space(3))) void*)                           \
              &tile[(pb) * 12288 + seg_ * 512 + lane * 8],                    \
          16, 0, 0);                                                          \
    }                                                                         \
  }

__global__ __launch_bounds__(512, 4) void attn_mfma_kernel(
    const ushort* __restrict__ Qb, const ushort* __restrict__ Sb,
    const int* __restrict__ labels, float* __restrict__ partial,
    int nq, int D) {
  __shared__ ushort tile[2 * 12288];
  __shared__ int lab[256];
  float* buckets = (float*)tile;
  const int tid = threadIdx.x;
  const int wave = tid >> 6, lane = tid & 63;
  const int fr = lane & 15, kg = lane >> 4;
  const int wr = wave >> 2, wc = wave & 3;
  const long q0 = (long)blockIdx.x * 128;
  const int part = blockIdx.y;
  const long s0 = (long)part * 256;

  f32x4 acc[4][4];
#pragma unroll
  for (int rg = 0; rg < 4; rg++)
#pragma unroll
    for (int cg = 0; cg < 4; cg++) acc[rg][cg] = (f32x4){0.f, 0.f, 0.f, 0.f};

  STAGE_BODY(0, 0)
  for (int t = 0; t < 16; t++) {
    const int p = t & 1;
    asm volatile("s_waitcnt vmcnt(0)" ::: "memory");
    __builtin_amdgcn_sched_barrier(0);
    __builtin_amdgcn_s_barrier();
    if (t < 15) STAGE_BODY(t + 1, p ^ 1)
    const ushort* base = &tile[p * 12288];
    bf16x8 bfr[4];
#pragma unroll
    for (int cg = 0; cg < 4; cg++)
      bfr[cg] = *(const bf16x8*)&base[(8 + wc * 4 + cg) * 512 + lane * 8];
#pragma unroll
    for (int rg = 0; rg < 4; rg++) {
      bf16x8 af = *(const bf16x8*)&base[(wr * 4 + rg) * 512 + lane * 8];
#pragma unroll
      for (int cg = 0; cg < 4; cg++)
        acc[rg][cg] = __builtin_amdgcn_mfma_f32_16x16x32_bf16(
            af, bfr[cg], acc[rg][cg], 0, 0, 0);
    }
  }

  __syncthreads();
  for (int i = tid; i < 128 * 65; i += 512) buckets[i] = 0.0f;
  if (tid < 256) lab[tid] = labels[s0 + tid];
  __syncthreads();
#pragma unroll
  for (int cg = 0; cg < 4; cg++) {
    int lb = lab[wc * 64 + cg * 16 + fr];
#pragma unroll
    for (int rg = 0; rg < 4; rg++)
#pragma unroll
      for (int r = 0; r < 4; r++)
        atomicAdd(&buckets[(wr * 64 + rg * 16 + kg * 4 + r) * 65 + lb],
                  __expf(acc[rg][cg][r]));
  }
  __syncthreads();
  for (int i = tid; i < 128 * 64; i += 512) {
    int q = i >> 6, c = i & 63;
    partial[((size_t)part * nq + (q0 + q)) * 64 + c] = buckets[q * 65 + c];
  }
}

// ---------------------------------------------------------------------------
// DIAGNOSTIC A: K-loop (stage + ds_read + MFMA) amplified x4 = 64 steps.
// Reads as 4L in the profile; identical steady-state rhythm to the real loop.
// ---------------------------------------------------------------------------
__global__ __launch_bounds__(512, 4) void attn_loop_only(
    const ushort* __restrict__ Qb, const ushort* __restrict__ Sb,
    float* __restrict__ sink, int D) {
  __shared__ ushort tile[2 * 12288];
  const int tid = threadIdx.x;
  const int wave = tid >> 6, lane = tid & 63;
  const int fr = lane & 15, kg = lane >> 4;
  const int wr = wave >> 2, wc = wave & 3;
  const long q0 = (long)blockIdx.x * 128;
  const long s0 = (long)blockIdx.y * 256;

  f32x4 acc[4][4];
#pragma unroll
  for (int rg = 0; rg < 4; rg++)
#pragma unroll
    for (int cg = 0; cg < 4; cg++) acc[rg][cg] = (f32x4){0.f, 0.f, 0.f, 0.f};

  STAGE_BODY(0, 0)
  for (int tt = 0; tt < 64; tt++) {          // 4 x 16 K-steps
    const int p = tt & 1;
    asm volatile("s_waitcnt vmcnt(0)" ::: "memory");
    __builtin_amdgcn_sched_barrier(0);
    __builtin_amdgcn_s_barrier();
    if (tt < 63) STAGE_BODY((tt + 1) & 15, p ^ 1)
    const ushort* base = &tile[p * 12288];
    bf16x8 bfr[4];
#pragma unroll
    for (int cg = 0; cg < 4; cg++)
      bfr[cg] = *(const bf16x8*)&base[(8 + wc * 4 + cg) * 512 + lane * 8];
#pragma unroll
    for (int rg = 0; rg < 4; rg++) {
      bf16x8 af = *(const bf16x8*)&base[(wr * 4 + rg) * 512 + lane * 8];
#pragma unroll
      for (int cg = 0; cg < 4; cg++)
        acc[rg][cg] = __builtin_amdgcn_mfma_f32_16x16x32_bf16(
            af, bfr[cg], acc[rg][cg], 0, 0, 0);
    }
  }
  float s = 0.f;
#pragma unroll
  for (int rg = 0; rg < 4; rg++)
#pragma unroll
    for (int cg = 0; cg < 4; cg++)
#pragma unroll
      for (int r = 0; r < 4; r++) s += acc[rg][cg][r];
  asm volatile("" :: "v"(s));            // rule #17: keep MFMAs live
  if (s == -1234.5f) sink[tid] = s;
}

// ---------------------------------------------------------------------------
// DIAGNOSTIC B: epilogue (exp + LDS atomics + store) amplified x8.
// Reads as 8E in the profile.
// ---------------------------------------------------------------------------
__global__ __launch_bounds__(512, 4) void attn_epi_only(
    const int* __restrict__ labels, float* __restrict__ partial, int nq) {
  __shared__ float buckets[128][65];
  __shared__ int lab[256];
  const int tid = threadIdx.x;
  const int wave = tid >> 6, lane = tid & 63;
  const int fr = lane & 15, kg = lane >> 4;
  const int wr = wave >> 2, wc = wave & 3;
  const long q0 = (long)blockIdx.x * 128;
  const int part = blockIdx.y;
  const long s0 = (long)part * 256;

  float accf[4][4][4];
#pragma unroll
  for (int rg = 0; rg < 4; rg++)
#pragma unroll
    for (int cg = 0; cg < 4; cg++)
#pragma unroll
      for (int r = 0; r < 4; r++)
        asm volatile("v_mov_b32 %0, 0" : "=v"(accf[rg][cg][r]));  // opaque 0.0f

  for (int i = tid; i < 128 * 65; i += 512) ((float*)buckets)[i] = 0.0f;
  if (tid < 256) lab[tid] = labels[s0 + tid];
  __syncthreads();
  for (int rep = 0; rep < 8; rep++) {        // x8 amplification
#pragma unroll
    for (int cg = 0; cg < 4; cg++) {
      int lb = lab[wc * 64 + cg * 16 + fr];
#pragma unroll
      for (int rg = 0; rg < 4; rg++)
#pragma unroll
        for (int r = 0; r < 4; r++)
          atomicAdd(&buckets[(wr * 64 + rg * 16 + kg * 4 + r)][lb],
                    __expf(accf[rg][cg][r]));
    }
  }
  __syncthreads();
  for (int i = tid; i < 128 * 64; i += 512) {
    int q = i >> 6, c = i & 63;
    partial[((size_t)part * nq + (q0 + q)) * 64 + c] = buckets[q][c];
  }
}

// ---------------------------------------------------------------------------
__global__ __launch_bounds__(256) void combine_kernel(
    const float* __restrict__ partial, float* __restrict__ out, int nq, int nsplit) {
  int q = (int)((blockIdx.x * blockDim.x + threadIdx.x) >> 6);
  int lane = threadIdx.x & 63;
  if (q >= nq) return;
  float v = 0.0f;
  for (int h = 0; h < nsplit; h++)
    v += partial[((size_t)h * nq + q) * 64 + lane];
  float s = v;
#pragma unroll
  for (int off = 32; off > 0; off >>= 1) s += __shfl_xor(s, off);
  out[(size_t)q * 64 + lane] = v / s;
}

// ---------------------------------------------------------------------------
// Workspace: [0,8M) xb_s  [8M,24M) xb_q  [24M,25M) Wt  [25M,33M) s_emb
// [33M,49M) q_emb; after encode+norm: s_bf [0,4M), q_bf [4M,12M),
// partial [12M,45.5M). Diagnostics run AFTER combine (outputs dead):
// readout = dur_total - 363 = 4L + 8E; top-5 identifies max(4L, 8E) by name.
// ---------------------------------------------------------------------------
extern "C" void kernel_launch(void* const* d_in, const int* in_sizes, int n_in,
                              void* d_out, int out_size, void* d_ws, size_t ws_size,
                              hipStream_t stream) {
  const float* support = (const float*)d_in[0];
  const float* query   = (const float*)d_in[1];
  const float* W       = (const float*)d_in[2];
  const float* b       = (const float*)d_in[3];
  const int*   labels  = (const int*)d_in[4];

  const int d_dim    = in_sizes[3];            // 512
  const int in_dim   = in_sizes[2] / d_dim;    // 1024
  const int n_support = in_sizes[0] / in_dim;  // 4096
  const int n_query   = in_sizes[1] / in_dim;  // 8192

  char* base = (char*)d_ws;
  ushort* xb_s  = (ushort*)(base);
  ushort* xb_q  = (ushort*)(base + ((size_t)8 << 20));
  ushort* Wt    = (ushort*)(base + ((size_t)24 << 20));
  float*  s_emb = (float*)(base + ((size_t)25 << 20));
  float*  q_emb = (float*)(base + ((size_t)33 << 20));
  ushort* s_bf  = (ushort*)(base);
  ushort* q_bf  = (ushort*)(base + ((size_t)4 << 20));
  float*  partial = (float*)(base + ((size_t)12 << 20));
  float*  sink    = (float*)(base + ((size_t)46 << 20));

  dim3 blk(256);
  cast_bf16_kernel<<<2048, blk, 0, stream>>>(support, xb_s, (size_t)n_support * in_dim / 4);
  cast_bf16_kernel<<<2048, blk, 0, stream>>>(query, xb_q, (size_t)n_query * in_dim / 4);
  transpose_cast_kernel<<<dim3(in_dim / 64, d_dim / 64), blk, 0, stream>>>(W, Wt, in_dim, d_dim);
  encode_mfma_kernel<<<dim3(n_support / 64, d_dim / 64), blk, 0, stream>>>(
      xb_s, Wt, b, s_emb, in_dim, d_dim);
  encode_mfma_kernel<<<dim3(n_query / 64, d_dim / 64), blk, 0, stream>>>(
      xb_q, Wt, b, q_emb, in_dim, d_dim);
  norm_bf16_kernel<<<dim3(n_support / 4), blk, 0, stream>>>(s_emb, s_bf, n_support, d_dim);
  norm_bf16_kernel<<<dim3(n_query / 4), blk, 0, stream>>>(q_emb, q_bf, n_query, d_dim);
  attn_mfma_kernel<<<dim3(n_query / 128, NPART), dim3(512), 0, stream>>>(
      q_bf, s_bf, labels, partial, n_query, d_dim);
  combine_kernel<<<dim3(n_query / 4), blk, 0, stream>>>(partial, (float*)d_out, n_query, NPART);

  // ---- amplified diagnostics (output-dead) ----
  attn_loop_only<<<dim3(n_query / 128, NPART), dim3(512), 0, stream>>>(
      q_bf, s_bf, sink, d_dim);   // ~4L
  attn_epi_only<<<dim3(n_query / 128, NPART), dim3(512), 0, stream>>>(
      labels, partial, n_query);  // ~8E
}

// Round 13
// 205.642 us; speedup vs baseline: 9.1440x; 9.1440x over previous
//
#include <hip/hip_runtime.h>
#include <hip/hip_bf16.h>
#include <math.h>

#define NPART 16  // s-blocks of 256: 64x16 = 1024 blocks

typedef __attribute__((ext_vector_type(8))) short bf16x8;  // MFMA A/B frag (4 VGPR)
typedef __attribute__((ext_vector_type(4))) float f32x4;   // MFMA C/D frag

static __device__ inline ushort f2bf(float x) {
  __hip_bfloat16 h = __float2bfloat16(x);
  return *reinterpret_cast<ushort*>(&h);
}

// ---------------------------------------------------------------------------
__global__ __launch_bounds__(256) void cast_bf16_kernel(
    const float* __restrict__ in, ushort* __restrict__ out, size_t n4) {
  size_t i = (size_t)blockIdx.x * blockDim.x + threadIdx.x;
  size_t stride = (size_t)gridDim.x * blockDim.x;
  for (; i < n4; i += stride) {
    float4 v = ((const float4*)in)[i];
    ushort4 u;
    u.x = f2bf(v.x); u.y = f2bf(v.y); u.z = f2bf(v.z); u.w = f2bf(v.w);
    ((ushort4*)out)[i] = u;
  }
}

// ---------------------------------------------------------------------------
__global__ __launch_bounds__(256) void transpose_cast_kernel(
    const float* __restrict__ W, ushort* __restrict__ Wt, int K, int D) {
  __shared__ float t[64][65];
  const int k0 = blockIdx.x * 64, d0 = blockIdx.y * 64;
  const int r = threadIdx.x >> 6, c = threadIdx.x & 63;
#pragma unroll
  for (int i = 0; i < 16; i++)
    t[r + i * 4][c] = W[(size_t)(k0 + r + i * 4) * D + d0 + c];
  __syncthreads();
#pragma unroll
  for (int i = 0; i < 16; i++)
    Wt[(size_t)(d0 + r + i * 4) * K + k0 + c] = f2bf(t[c][r + i * 4]);
}

// ---------------------------------------------------------------------------
__global__ __launch_bounds__(256) void encode_mfma_kernel(
    const ushort* __restrict__ Xb, const ushort* __restrict__ Wt,
    const float* __restrict__ bias, float* __restrict__ emb,
    int K, int D) {
  const int tid = threadIdx.x;
  const int wave = tid >> 6, lane = tid & 63;
  const int fr = lane & 15, kg = lane >> 4;
  const long row0 = (long)blockIdx.x * 64, col0 = (long)blockIdx.y * 64;

  f32x4 acc[4];
#pragma unroll
  for (int c = 0; c < 4; c++) acc[c] = (f32x4){0.f, 0.f, 0.f, 0.f};

  const ushort* xrow = Xb + (row0 + wave * 16 + fr) * (size_t)K;
  const int nt = K / 32;
  for (int t = 0; t < nt; t++) {
    bf16x8 af = *(const bf16x8*)(xrow + t * 32 + kg * 8);
#pragma unroll
    for (int c = 0; c < 4; c++) {
      const ushort* wrow = Wt + (col0 + c * 16 + fr) * (size_t)K;
      bf16x8 bf = *(const bf16x8*)(wrow + t * 32 + kg * 8);
      acc[c] = __builtin_amdgcn_mfma_f32_16x16x32_bf16(af, bf, acc[c], 0, 0, 0);
    }
  }
#pragma unroll
  for (int c = 0; c < 4; c++) {
    float bl = bias[col0 + c * 16 + fr];
#pragma unroll
    for (int r = 0; r < 4; r++)
      emb[(row0 + wave * 16 + kg * 4 + r) * (size_t)D + col0 + c * 16 + fr] =
          acc[c][r] + bl;
  }
}

// ---------------------------------------------------------------------------
__global__ __launch_bounds__(256) void norm_bf16_kernel(
    const float* __restrict__ in, ushort* __restrict__ outb, int nrows, int D) {
  int row = (int)((blockIdx.x * blockDim.x + threadIdx.x) >> 6);
  int lane = threadIdx.x & 63;
  if (row >= nrows) return;
  const float4* p = (const float4*)(in + (size_t)row * D);
  float4 v0 = p[lane];
  float4 v1 = p[lane + 64];
  float ss = v0.x * v0.x + v0.y * v0.y + v0.z * v0.z + v0.w * v0.w
           + v1.x * v1.x + v1.y * v1.y + v1.z * v1.z + v1.w * v1.w;
#pragma unroll
  for (int off = 32; off > 0; off >>= 1) ss += __shfl_xor(ss, off);
  float inv = 1.0f / fmaxf(sqrtf(ss), 1e-12f);
  ushort4 u0, u1;
  u0.x = f2bf(v0.x * inv); u0.y = f2bf(v0.y * inv);
  u0.z = f2bf(v0.z * inv); u0.w = f2bf(v0.w * inv);
  u1.x = f2bf(v1.x * inv); u1.y = f2bf(v1.y * inv);
  u1.z = f2bf(v1.z * inv); u1.w = f2bf(v1.w * inv);
  ushort* o = outb + (size_t)row * D;
  *(ushort4*)(o + 4 * lane) = u0;
  *(ushort4*)(o + 256 + 4 * lane) = u1;
}

// ---------------------------------------------------------------------------
// MFMA attention, ATOMIC-FREE epilogue (r12 diagnostic: epilogue was 168 of
// 224 us — ds_atomic serialization, not the GEMM loop).
// Phase 1: K-loop (r10 structure, unchanged, proven): scores acc[4][4].
// Phase 2: P = exp(scores) as bf16 -> LDS tile (reuses staging memory),
//          XOR-swizzled: byte = (q<<9 | s<<1) ^ ((q&7)<<4)  [bijective:
//          q in bits>=9, s in bits 1..8, XOR touches bits 4..6 only].
// Phase 3: predictions_partial = P @ onehot(labels) via second MFMA chain
//          (K=256): A = P from LDS (swizzled ds_read_b128, ~2-way = free),
//          B = onehot built in regs (exact in bf16), f32 accumulate,
//          coalesced direct stores. Sum over classes == sum of P exactly,
//          so combine's row-sum denominator stays correct.
// ---------------------------------------------------------------------------
#define STAGE_BODY(kt, pb)                                                    \
  {                                                                           \
    _Pragma("unroll")                                                         \
    for (int i_ = 0; i_ < 3; i_++) {                                          \
      const int seg_ = wave * 3 + i_;                                         \
      const ushort* src_ = (seg_ < 8)                                         \
          ? Qb + (q0 + seg_ * 16 + fr) * (size_t)D + (kt) * 32 + kg * 8       \
          : Sb + (s0 + (seg_ - 8) * 16 + fr) * (size_t)D + (kt) * 32 + kg * 8;\
      __builtin_amdgcn_global_load_lds(                                       \
          (const __attribute__((address_space(1))) void*)src_,                \
          (__attribute__((address_space(3))) void*)                           \
              &tile[(pb) * 12288 + seg_ * 512 + lane * 8],                    \
          16, 0, 0);                                                          \
    }                                                                         \
  }

__global__ __launch_bounds__(512, 4) void attn_mfma_kernel(
    const ushort* __restrict__ Qb, const ushort* __restrict__ Sb,
    const int* __restrict__ labels, float* __restrict__ partial,
    int nq, int D) {
  __shared__ ushort tile[32768];   // phase1: 2x12288 staging; phase2/3: P[128][256]
  __shared__ int lab[256];
  const int tid = threadIdx.x;
  const int wave = tid >> 6, lane = tid & 63;
  const int fr = lane & 15, kg = lane >> 4;
  const int wr = wave >> 2, wc = wave & 3;
  const long q0 = (long)blockIdx.x * 128;
  const int part = blockIdx.y;
  const long s0 = (long)part * 256;

  if (tid < 256) lab[tid] = labels[s0 + tid];

  f32x4 acc[4][4];
#pragma unroll
  for (int rg = 0; rg < 4; rg++)
#pragma unroll
    for (int cg = 0; cg < 4; cg++) acc[rg][cg] = (f32x4){0.f, 0.f, 0.f, 0.f};

  // ---- phase 1: score GEMM (unchanged r10 2-phase pipeline) ----
  STAGE_BODY(0, 0)
  for (int t = 0; t < 16; t++) {
    const int p = t & 1;
    asm volatile("s_waitcnt vmcnt(0)" ::: "memory");
    __builtin_amdgcn_sched_barrier(0);
    __builtin_amdgcn_s_barrier();
    if (t < 15) STAGE_BODY(t + 1, p ^ 1)
    const ushort* base = &tile[p * 12288];
    bf16x8 bfr[4];
#pragma unroll
    for (int cg = 0; cg < 4; cg++)
      bfr[cg] = *(const bf16x8*)&base[(8 + wc * 4 + cg) * 512 + lane * 8];
#pragma unroll
    for (int rg = 0; rg < 4; rg++) {
      bf16x8 af = *(const bf16x8*)&base[(wr * 4 + rg) * 512 + lane * 8];
#pragma unroll
      for (int cg = 0; cg < 4; cg++)
        acc[rg][cg] = __builtin_amdgcn_mfma_f32_16x16x32_bf16(
            af, bfr[cg], acc[rg][cg], 0, 0, 0);
    }
  }

  // ---- phase 2: P = exp(S) bf16 -> swizzled LDS ----
  __syncthreads();   // all tile reads done before overwrite
#pragma unroll
  for (int rg = 0; rg < 4; rg++)
#pragma unroll
    for (int cg = 0; cg < 4; cg++)
#pragma unroll
      for (int r = 0; r < 4; r++) {
        const int q  = wr * 64 + rg * 16 + kg * 4 + r;
        const int sc = wc * 64 + cg * 16 + fr;
        const int byteoff = ((q << 9) + (sc << 1)) ^ ((q & 7) << 4);
        *(ushort*)((char*)tile + byteoff) = f2bf(__expf(acc[rg][cg][r]));
      }
  __syncthreads();   // P complete before cross-wave reads

  // ---- phase 3: out = P @ onehot, K=256 (8 k-steps) ----
  f32x4 acc2[4];
#pragma unroll
  for (int rg = 0; rg < 4; rg++) acc2[rg] = (f32x4){0.f, 0.f, 0.f, 0.f};
  const int cls = wc * 16 + fr;
#pragma unroll
  for (int t = 0; t < 8; t++) {
    const int kb = t * 32 + kg * 8;
    int4 l0 = *(const int4*)&lab[kb];       // broadcast reads (uniform per kg)
    int4 l1 = *(const int4*)&lab[kb + 4];
    uint b0 = ((l0.x == cls) ? 0x3F80u : 0u) | (((l0.y == cls) ? 0x3F80u : 0u) << 16);
    uint b1 = ((l0.z == cls) ? 0x3F80u : 0u) | (((l0.w == cls) ? 0x3F80u : 0u) << 16);
    uint b2 = ((l1.x == cls) ? 0x3F80u : 0u) | (((l1.y == cls) ? 0x3F80u : 0u) << 16);
    uint b3 = ((l1.z == cls) ? 0x3F80u : 0u) | (((l1.w == cls) ? 0x3F80u : 0u) << 16);
    uint4 bu = {b0, b1, b2, b3};
    bf16x8 bfr = *(bf16x8*)&bu;             // onehot B-frag (exact in bf16)
#pragma unroll
    for (int rg = 0; rg < 4; rg++) {
      const int qrow = wr * 64 + rg * 16 + fr;
      const int byteoff = ((qrow << 9) + (kb << 1)) ^ ((qrow & 7) << 4);
      bf16x8 af = *(const bf16x8*)((char*)tile + byteoff);
      acc2[rg] = __builtin_amdgcn_mfma_f32_16x16x32_bf16(af, bfr, acc2[rg], 0, 0, 0);
    }
  }
  // store: D layout col=cls, row=kg*4+r -> coalesced 64B runs per 16 lanes
#pragma unroll
  for (int rg = 0; rg < 4; rg++)
#pragma unroll
    for (int r = 0; r < 4; r++) {
      const long q = q0 + wr * 64 + rg * 16 + kg * 4 + r;
      partial[((size_t)part * nq + q) * 64 + cls] = acc2[rg][r];
    }
}

// ---------------------------------------------------------------------------
__global__ __launch_bounds__(256) void combine_kernel(
    const float* __restrict__ partial, float* __restrict__ out, int nq, int nsplit) {
  int q = (int)((blockIdx.x * blockDim.x + threadIdx.x) >> 6);
  int lane = threadIdx.x & 63;
  if (q >= nq) return;
  float v = 0.0f;
  for (int h = 0; h < nsplit; h++)
    v += partial[((size_t)h * nq + q) * 64 + lane];
  float s = v;
#pragma unroll
  for (int off = 32; off > 0; off >>= 1) s += __shfl_xor(s, off);
  out[(size_t)q * 64 + lane] = v / s;
}

// ---------------------------------------------------------------------------
// Workspace: [0,8M) xb_s  [8M,24M) xb_q  [24M,25M) Wt  [25M,33M) s_emb
// [33M,49M) q_emb; after encode+norm: s_bf [0,4M), q_bf [4M,12M),
// partial [12M,44M). All regions rewritten every call; aliases reuse only
// dead buffers; d_out fully overwritten by combine.
// ---------------------------------------------------------------------------
extern "C" void kernel_launch(void* const* d_in, const int* in_sizes, int n_in,
                              void* d_out, int out_size, void* d_ws, size_t ws_size,
                              hipStream_t stream) {
  const float* support = (const float*)d_in[0];
  const float* query   = (const float*)d_in[1];
  const float* W       = (const float*)d_in[2];
  const float* b       = (const float*)d_in[3];
  const int*   labels  = (const int*)d_in[4];

  const int d_dim    = in_sizes[3];            // 512
  const int in_dim   = in_sizes[2] / d_dim;    // 1024
  const int n_support = in_sizes[0] / in_dim;  // 4096
  const int n_query   = in_sizes[1] / in_dim;  // 8192

  char* base = (char*)d_ws;
  ushort* xb_s  = (ushort*)(base);
  ushort* xb_q  = (ushort*)(base + ((size_t)8 << 20));
  ushort* Wt    = (ushort*)(base + ((size_t)24 << 20));
  float*  s_emb = (float*)(base + ((size_t)25 << 20));
  float*  q_emb = (float*)(base + ((size_t)33 << 20));
  ushort* s_bf  = (ushort*)(base);                        // alias xb_s (dead)
  ushort* q_bf  = (ushort*)(base + ((size_t)4 << 20));    // alias xb (dead)
  float*  partial = (float*)(base + ((size_t)12 << 20));  // alias xb/Wt/emb (dead)

  dim3 blk(256);
  cast_bf16_kernel<<<2048, blk, 0, stream>>>(support, xb_s, (size_t)n_support * in_dim / 4);
  cast_bf16_kernel<<<2048, blk, 0, stream>>>(query, xb_q, (size_t)n_query * in_dim / 4);
  transpose_cast_kernel<<<dim3(in_dim / 64, d_dim / 64), blk, 0, stream>>>(W, Wt, in_dim, d_dim);
  encode_mfma_kernel<<<dim3(n_support / 64, d_dim / 64), blk, 0, stream>>>(
      xb_s, Wt, b, s_emb, in_dim, d_dim);
  encode_mfma_kernel<<<dim3(n_query / 64, d_dim / 64), blk, 0, stream>>>(
      xb_q, Wt, b, q_emb, in_dim, d_dim);
  norm_bf16_kernel<<<dim3(n_support / 4), blk, 0, stream>>>(s_emb, s_bf, n_support, d_dim);
  norm_bf16_kernel<<<dim3(n_query / 4), blk, 0, stream>>>(q_emb, q_bf, n_query, d_dim);
  attn_mfma_kernel<<<dim3(n_query / 128, NPART), dim3(512), 0, stream>>>(
      q_bf, s_bf, labels, partial, n_query, d_dim);
  combine_kernel<<<dim3(n_query / 4), blk, 0, stream>>>(partial, (float*)d_out, n_query, NPART);
}

// Round 15
// 127.591 us; speedup vs baseline: 14.7376x; 1.6117x over previous
//
#include <hip/hip_runtime.h>
#include <hip/hip_bf16.h>
#include <math.h>

#define NPART 16  // s-blocks of 256: 64x16 = 1024 blocks

typedef __attribute__((ext_vector_type(8))) short bf16x8;  // MFMA A/B frag (4 VGPR)
typedef __attribute__((ext_vector_type(4))) float f32x4;   // MFMA C/D frag

static __device__ inline ushort f2bf(float x) {
  __hip_bfloat16 h = __float2bfloat16(x);
  return *reinterpret_cast<ushort*>(&h);
}

// ---------------------------------------------------------------------------
__global__ __launch_bounds__(256) void cast_bf16_kernel(
    const float* __restrict__ in, ushort* __restrict__ out, size_t n4) {
  size_t i = (size_t)blockIdx.x * blockDim.x + threadIdx.x;
  size_t stride = (size_t)gridDim.x * blockDim.x;
  for (; i < n4; i += stride) {
    float4 v = ((const float4*)in)[i];
    ushort4 u;
    u.x = f2bf(v.x); u.y = f2bf(v.y); u.z = f2bf(v.z); u.w = f2bf(v.w);
    ((ushort4*)out)[i] = u;
  }
}

// ---------------------------------------------------------------------------
__global__ __launch_bounds__(256) void transpose_cast_kernel(
    const float* __restrict__ W, ushort* __restrict__ Wt, int K, int D) {
  __shared__ float t[64][65];
  const int k0 = blockIdx.x * 64, d0 = blockIdx.y * 64;
  const int r = threadIdx.x >> 6, c = threadIdx.x & 63;
#pragma unroll
  for (int i = 0; i < 16; i++)
    t[r + i * 4][c] = W[(size_t)(k0 + r + i * 4) * D + d0 + c];
  __syncthreads();
#pragma unroll
  for (int i = 0; i < 16; i++)
    Wt[(size_t)(d0 + r + i * 4) * K + k0 + c] = f2bf(t[c][r + i * 4]);
}

// ---------------------------------------------------------------------------
// FUSED encoder GEMM — direct port of the attn phase-1 pipeline (r10-proven):
// 512 threads (8 waves 2x4), tile 128 rows x 256 cols, BK=32, 32 K-steps,
// double-buffered fragment-order global_load_lds staging, 2-phase loop.
// Xall = [n_support+n_query][1024] bf16 (contiguous in ws); Wt = [512][1024].
// emb = [rows][512] f32 (s_emb/q_emb contiguous). Epilogue adds bias.
// acc[rg][cg][r] = out(row0+wr*64+rg*16+kg*4+r, d0+wc*64+cg*16+fr).
// ---------------------------------------------------------------------------
#define ESTAGE(kt, pb)                                                        \
  {                                                                           \
    _Pragma("unroll")                                                         \
    for (int i_ = 0; i_ < 3; i_++) {                                          \
      const int seg_ = wave * 3 + i_;                                         \
      const ushort* src_ = (seg_ < 8)                                         \
          ? Xall + (row0 + seg_ * 16 + fr) * (size_t)K + (kt) * 32 + kg * 8   \
          : Wt + (d0 + (seg_ - 8) * 16 + fr) * (size_t)K + (kt) * 32 + kg * 8;\
      __builtin_amdgcn_global_load_lds(                                       \
          (const __attribute__((address_space(1))) void*)src_,                \
          (__attribute__((address_space(3))) void*)                           \
              &tile[(pb) * 12288 + seg_ * 512 + lane * 8],                    \
          16, 0, 0);                                                          \
    }                                                                         \
  }

__global__ __launch_bounds__(512, 4) void encode_mfma_kernel(
    const ushort* __restrict__ Xall, const ushort* __restrict__ Wt,
    const float* __restrict__ bias, float* __restrict__ emb,
    int K, int D) {
  __shared__ ushort tile[2 * 12288];
  const int tid = threadIdx.x;
  const int wave = tid >> 6, lane = tid & 63;
  const int fr = lane & 15, kg = lane >> 4;
  const int wr = wave >> 2, wc = wave & 3;
  const long row0 = (long)blockIdx.x * 128;
  const int d0 = blockIdx.y * 256;

  f32x4 acc[4][4];
#pragma unroll
  for (int rg = 0; rg < 4; rg++)
#pragma unroll
    for (int cg = 0; cg < 4; cg++) acc[rg][cg] = (f32x4){0.f, 0.f, 0.f, 0.f};

  ESTAGE(0, 0)
  for (int t = 0; t < 32; t++) {     // K = 1024 = 32 x BK(32)
    const int p = t & 1;
    asm volatile("s_waitcnt vmcnt(0)" ::: "memory");
    __builtin_amdgcn_sched_barrier(0);
    __builtin_amdgcn_s_barrier();
    if (t < 31) ESTAGE(t + 1, p ^ 1)
    const ushort* base = &tile[p * 12288];
    bf16x8 bfr[4];
#pragma unroll
    for (int cg = 0; cg < 4; cg++)
      bfr[cg] = *(const bf16x8*)&base[(8 + wc * 4 + cg) * 512 + lane * 8];
#pragma unroll
    for (int rg = 0; rg < 4; rg++) {
      bf16x8 af = *(const bf16x8*)&base[(wr * 4 + rg) * 512 + lane * 8];
#pragma unroll
      for (int cg = 0; cg < 4; cg++)
        acc[rg][cg] = __builtin_amdgcn_mfma_f32_16x16x32_bf16(
            af, bfr[cg], acc[rg][cg], 0, 0, 0);
    }
  }
#pragma unroll
  for (int cg = 0; cg < 4; cg++) {
    const int col = d0 + wc * 64 + cg * 16 + fr;
    const float bl = bias[col];
#pragma unroll
    for (int rg = 0; rg < 4; rg++)
#pragma unroll
      for (int r = 0; r < 4; r++)
        emb[(row0 + wr * 64 + rg * 16 + kg * 4 + r) * (size_t)D + col] =
            acc[rg][cg][r] + bl;
  }
}

// ---------------------------------------------------------------------------
__global__ __launch_bounds__(256) void norm_bf16_kernel(
    const float* __restrict__ in, ushort* __restrict__ outb, int nrows, int D) {
  int row = (int)((blockIdx.x * blockDim.x + threadIdx.x) >> 6);
  int lane = threadIdx.x & 63;
  if (row >= nrows) return;
  const float4* p = (const float4*)(in + (size_t)row * D);
  float4 v0 = p[lane];
  float4 v1 = p[lane + 64];
  float ss = v0.x * v0.x + v0.y * v0.y + v0.z * v0.z + v0.w * v0.w
           + v1.x * v1.x + v1.y * v1.y + v1.z * v1.z + v1.w * v1.w;
#pragma unroll
  for (int off = 32; off > 0; off >>= 1) ss += __shfl_xor(ss, off);
  float inv = 1.0f / fmaxf(sqrtf(ss), 1e-12f);
  ushort4 u0, u1;
  u0.x = f2bf(v0.x * inv); u0.y = f2bf(v0.y * inv);
  u0.z = f2bf(v0.z * inv); u0.w = f2bf(v0.w * inv);
  u1.x = f2bf(v1.x * inv); u1.y = f2bf(v1.y * inv);
  u1.z = f2bf(v1.z * inv); u1.w = f2bf(v1.w * inv);
  ushort* o = outb + (size_t)row * D;
  *(ushort4*)(o + 4 * lane) = u0;
  *(ushort4*)(o + 256 + 4 * lane) = u1;
}

// ---------------------------------------------------------------------------
// MFMA attention, atomic-free epilogue (r13-proven, unchanged).
// ---------------------------------------------------------------------------
#define STAGE_BODY(kt, pb)                                                    \
  {                                                                           \
    _Pragma("unroll")                                                         \
    for (int i_ = 0; i_ < 3; i_++) {                                          \
      const int seg_ = wave * 3 + i_;                                         \
      const ushort* src_ = (seg_ < 8)                                         \
          ? Qb + (q0 + seg_ * 16 + fr) * (size_t)D + (kt) * 32 + kg * 8       \
          : Sb + (s0 + (seg_ - 8) * 16 + fr) * (size_t)D + (kt) * 32 + kg * 8;\
      __builtin_amdgcn_global_load_lds(                                       \
          (const __attribute__((address_space(1))) void*)src_,                \
          (__attribute__((address_space(3))) void*)                           \
              &tile[(pb) * 12288 + seg_ * 512 + lane * 8],                    \
          16, 0, 0);                                                          \
    }                                                                         \
  }

__global__ __launch_bounds__(512, 4) void attn_mfma_kernel(
    const ushort* __restrict__ Qb, const ushort* __restrict__ Sb,
    const int* __restrict__ labels, float* __restrict__ partial,
    int nq, int D) {
  __shared__ ushort tile[32768];   // phase1: 2x12288 staging; phase2/3: P[128][256]
  __shared__ int lab[256];
  const int tid = threadIdx.x;
  const int wave = tid >> 6, lane = tid & 63;
  const int fr = lane & 15, kg = lane >> 4;
  const int wr = wave >> 2, wc = wave & 3;
  const long q0 = (long)blockIdx.x * 128;
  const int part = blockIdx.y;
  const long s0 = (long)part * 256;

  if (tid < 256) lab[tid] = labels[s0 + tid];

  f32x4 acc[4][4];
#pragma unroll
  for (int rg = 0; rg < 4; rg++)
#pragma unroll
    for (int cg = 0; cg < 4; cg++) acc[rg][cg] = (f32x4){0.f, 0.f, 0.f, 0.f};

  // ---- phase 1: score GEMM (r10 2-phase pipeline) ----
  STAGE_BODY(0, 0)
  for (int t = 0; t < 16; t++) {
    const int p = t & 1;
    asm volatile("s_waitcnt vmcnt(0)" ::: "memory");
    __builtin_amdgcn_sched_barrier(0);
    __builtin_amdgcn_s_barrier();
    if (t < 15) STAGE_BODY(t + 1, p ^ 1)
    const ushort* base = &tile[p * 12288];
    bf16x8 bfr[4];
#pragma unroll
    for (int cg = 0; cg < 4; cg++)
      bfr[cg] = *(const bf16x8*)&base[(8 + wc * 4 + cg) * 512 + lane * 8];
#pragma unroll
    for (int rg = 0; rg < 4; rg++) {
      bf16x8 af = *(const bf16x8*)&base[(wr * 4 + rg) * 512 + lane * 8];
#pragma unroll
      for (int cg = 0; cg < 4; cg++)
        acc[rg][cg] = __builtin_amdgcn_mfma_f32_16x16x32_bf16(
            af, bfr[cg], acc[rg][cg], 0, 0, 0);
    }
  }

  // ---- phase 2: P = exp(S) bf16 -> swizzled LDS ----
  __syncthreads();
#pragma unroll
  for (int rg = 0; rg < 4; rg++)
#pragma unroll
    for (int cg = 0; cg < 4; cg++)
#pragma unroll
      for (int r = 0; r < 4; r++) {
        const int q  = wr * 64 + rg * 16 + kg * 4 + r;
        const int sc = wc * 64 + cg * 16 + fr;
        const int byteoff = ((q << 9) + (sc << 1)) ^ ((q & 7) << 4);
        *(ushort*)((char*)tile + byteoff) = f2bf(__expf(acc[rg][cg][r]));
      }
  __syncthreads();

  // ---- phase 3: out = P @ onehot, K=256 (8 k-steps) ----
  f32x4 acc2[4];
#pragma unroll
  for (int rg = 0; rg < 4; rg++) acc2[rg] = (f32x4){0.f, 0.f, 0.f, 0.f};
  const int cls = wc * 16 + fr;
#pragma unroll
  for (int t = 0; t < 8; t++) {
    const int kb = t * 32 + kg * 8;
    int4 l0 = *(const int4*)&lab[kb];
    int4 l1 = *(const int4*)&lab[kb + 4];
    uint b0 = ((l0.x == cls) ? 0x3F80u : 0u) | (((l0.y == cls) ? 0x3F80u : 0u) << 16);
    uint b1 = ((l0.z == cls) ? 0x3F80u : 0u) | (((l0.w == cls) ? 0x3F80u : 0u) << 16);
    uint b2 = ((l1.x == cls) ? 0x3F80u : 0u) | (((l1.y == cls) ? 0x3F80u : 0u) << 16);
    uint b3 = ((l1.z == cls) ? 0x3F80u : 0u) | (((l1.w == cls) ? 0x3F80u : 0u) << 16);
    uint4 bu = {b0, b1, b2, b3};
    bf16x8 bfr = *(bf16x8*)&bu;
#pragma unroll
    for (int rg = 0; rg < 4; rg++) {
      const int qrow = wr * 64 + rg * 16 + fr;
      const int byteoff = ((qrow << 9) + (kb << 1)) ^ ((qrow & 7) << 4);
      bf16x8 af = *(const bf16x8*)((char*)tile + byteoff);
      acc2[rg] = __builtin_amdgcn_mfma_f32_16x16x32_bf16(af, bfr, acc2[rg], 0, 0, 0);
    }
  }
#pragma unroll
  for (int rg = 0; rg < 4; rg++)
#pragma unroll
    for (int r = 0; r < 4; r++) {
      const long q = q0 + wr * 64 + rg * 16 + kg * 4 + r;
      partial[((size_t)part * nq + q) * 64 + cls] = acc2[rg][r];
    }
}

// ---------------------------------------------------------------------------
__global__ __launch_bounds__(256) void combine_kernel(
    const float* __restrict__ partial, float* __restrict__ out, int nq, int nsplit) {
  int q = (int)((blockIdx.x * blockDim.x + threadIdx.x) >> 6);
  int lane = threadIdx.x & 63;
  if (q >= nq) return;
  float v = 0.0f;
  for (int h = 0; h < nsplit; h++)
    v += partial[((size_t)h * nq + q) * 64 + lane];
  float s = v;
#pragma unroll
  for (int off = 32; off > 0; off >>= 1) s += __shfl_xor(s, off);
  out[(size_t)q * 64 + lane] = v / s;
}

// ---------------------------------------------------------------------------
// Workspace: [0,8M) xb_s  [8M,24M) xb_q   (contiguous 12288x1024 bf16)
// [24M,25M) Wt  [25M,33M) s_emb  [33M,49M) q_emb (contiguous 12288x512 f32)
// after encode+norm: s_bf [0,4M), q_bf [4M,12M) (contiguous 12288x512 bf16),
// partial [12M,44M). All regions rewritten every call; aliases reuse only
// dead buffers; d_out fully overwritten by combine.
// ---------------------------------------------------------------------------
extern "C" void kernel_launch(void* const* d_in, const int* in_sizes, int n_in,
                              void* d_out, int out_size, void* d_ws, size_t ws_size,
                              hipStream_t stream) {
  const float* support = (const float*)d_in[0];
  const float* query   = (const float*)d_in[1];
  const float* W       = (const float*)d_in[2];
  const float* b       = (const float*)d_in[3];
  const int*   labels  = (const int*)d_in[4];

  const int d_dim    = in_sizes[3];            // 512
  const int in_dim   = in_sizes[2] / d_dim;    // 1024
  const int n_support = in_sizes[0] / in_dim;  // 4096
  const int n_query   = in_sizes[1] / in_dim;  // 8192
  const int n_all     = n_support + n_query;   // 12288

  char* base = (char*)d_ws;
  ushort* xb_s  = (ushort*)(base);                        // [0,8M) -- xb base
  ushort* xb_q  = (ushort*)(base + ((size_t)8 << 20));
  ushort* Wt    = (ushort*)(base + ((size_t)24 << 20));
  float*  s_emb = (float*)(base + ((size_t)25 << 20));    // emb base (24M B)
  float*  q_emb = (float*)(base + ((size_t)33 << 20));
  ushort* s_bf  = (ushort*)(base);                        // alias xb_s (dead)
  ushort* q_bf  = (ushort*)(base + ((size_t)4 << 20));    // alias xb (dead)
  float*  partial = (float*)(base + ((size_t)12 << 20));  // alias xb/Wt (dead)

  dim3 blk(256);
  cast_bf16_kernel<<<2048, blk, 0, stream>>>(support, xb_s, (size_t)n_support * in_dim / 4);
  cast_bf16_kernel<<<2048, blk, 0, stream>>>(query, xb_q, (size_t)n_query * in_dim / 4);
  transpose_cast_kernel<<<dim3(in_dim / 64, d_dim / 64), blk, 0, stream>>>(W, Wt, in_dim, d_dim);
  // fused encode: all 12288 rows, 128x256 tiles -> grid (96, 2)
  encode_mfma_kernel<<<dim3(n_all / 128, d_dim / 256), dim3(512), 0, stream>>>(
      xb_s, Wt, b, s_emb, in_dim, d_dim);
  // fused norm: 12288 contiguous rows f32 -> contiguous bf16
  norm_bf16_kernel<<<dim3(n_all / 4), blk, 0, stream>>>(s_emb, s_bf, n_all, d_dim);
  attn_mfma_kernel<<<dim3(n_query / 128, NPART), dim3(512), 0, stream>>>(
      q_bf, s_bf, labels, partial, n_query, d_dim);
  combine_kernel<<<dim3(n_query / 4), blk, 0, stream>>>(partial, (float*)d_out, n_query, NPART);
}

// Round 16
// 120.241 us; speedup vs baseline: 15.6385x; 1.0611x over previous
//
#include <hip/hip_runtime.h>
#include <hip/hip_bf16.h>
#include <math.h>

#define NPART 16  // s-blocks of 256: 64x16 = 1024 blocks

typedef __attribute__((ext_vector_type(8))) short bf16x8;  // MFMA A/B frag (4 VGPR)
typedef __attribute__((ext_vector_type(4))) float f32x4;   // MFMA C/D frag

static __device__ inline ushort f2bf(float x) {
  __hip_bfloat16 h = __float2bfloat16(x);
  return *reinterpret_cast<ushort*>(&h);
}

// ---------------------------------------------------------------------------
__global__ __launch_bounds__(256) void cast_bf16_kernel(
    const float* __restrict__ in, ushort* __restrict__ out, size_t n4) {
  size_t i = (size_t)blockIdx.x * blockDim.x + threadIdx.x;
  size_t stride = (size_t)gridDim.x * blockDim.x;
  for (; i < n4; i += stride) {
    float4 v = ((const float4*)in)[i];
    ushort4 u;
    u.x = f2bf(v.x); u.y = f2bf(v.y); u.z = f2bf(v.z); u.w = f2bf(v.w);
    ((ushort4*)out)[i] = u;
  }
}

// ---------------------------------------------------------------------------
__global__ __launch_bounds__(256) void transpose_cast_kernel(
    const float* __restrict__ W, ushort* __restrict__ Wt, int K, int D) {
  __shared__ float t[64][65];
  const int k0 = blockIdx.x * 64, d0 = blockIdx.y * 64;
  const int r = threadIdx.x >> 6, c = threadIdx.x & 63;
#pragma unroll
  for (int i = 0; i < 16; i++)
    t[r + i * 4][c] = W[(size_t)(k0 + r + i * 4) * D + d0 + c];
  __syncthreads();
#pragma unroll
  for (int i = 0; i < 16; i++)
    Wt[(size_t)(d0 + r + i * 4) * K + k0 + c] = f2bf(t[c][r + i * 4]);
}

// ---------------------------------------------------------------------------
// FUSED encoder GEMM (r15-proven structure) + T4 counted-vmcnt 3-buffer
// rotation: stage(t+2) issued per step, vmcnt(3) waits only stage(t) (the
// oldest 3 per-wave loads), leaving stage(t+1) in flight across the barrier
// -> ~2 compute phases of load-latency cover (was 1).
// ---------------------------------------------------------------------------
#define ESTAGE(kt, pb)                                                        \
  {                                                                           \
    _Pragma("unroll")                                                         \
    for (int i_ = 0; i_ < 3; i_++) {                                          \
      const int seg_ = wave * 3 + i_;                                         \
      const ushort* src_ = (seg_ < 8)                                         \
          ? Xall + (row0 + seg_ * 16 + fr) * (size_t)K + (kt) * 32 + kg * 8   \
          : Wt + (d0 + (seg_ - 8) * 16 + fr) * (size_t)K + (kt) * 32 + kg * 8;\
      __builtin_amdgcn_global_load_lds(                                       \
          (const __attribute__((address_space(1))) void*)src_,                \
          (__attribute__((address_space(3))) void*)                           \
              &tile[(pb) * 12288 + seg_ * 512 + lane * 8],                    \
          16, 0, 0);                                                          \
    }                                                                         \
  }

__global__ __launch_bounds__(512, 4) void encode_mfma_kernel(
    const ushort* __restrict__ Xall, const ushort* __restrict__ Wt,
    const float* __restrict__ bias, float* __restrict__ emb,
    int K, int D) {
  __shared__ ushort tile[3 * 12288];   // 72 KB, 3-deep rotation
  const int tid = threadIdx.x;
  const int wave = tid >> 6, lane = tid & 63;
  const int fr = lane & 15, kg = lane >> 4;
  const int wr = wave >> 2, wc = wave & 3;
  const long row0 = (long)blockIdx.x * 128;
  const int d0 = blockIdx.y * 256;

  f32x4 acc[4][4];
#pragma unroll
  for (int rg = 0; rg < 4; rg++)
#pragma unroll
    for (int cg = 0; cg < 4; cg++) acc[rg][cg] = (f32x4){0.f, 0.f, 0.f, 0.f};

  ESTAGE(0, 0)
  ESTAGE(1, 1)
  int bcur = 0;
  for (int t = 0; t < 32; t++) {     // K = 1024 = 32 x BK(32)
    if (t < 31) asm volatile("s_waitcnt vmcnt(3)" ::: "memory");  // stage(t) done
    else        asm volatile("s_waitcnt vmcnt(0)" ::: "memory");
    __builtin_amdgcn_sched_barrier(0);
    __builtin_amdgcn_s_barrier();
    if (t < 30) {
      int bnext = bcur + 2; if (bnext >= 3) bnext -= 3;
      ESTAGE(t + 2, bnext)
    }
    const ushort* base = &tile[bcur * 12288];
    bf16x8 bfr[4];
#pragma unroll
    for (int cg = 0; cg < 4; cg++)
      bfr[cg] = *(const bf16x8*)&base[(8 + wc * 4 + cg) * 512 + lane * 8];
#pragma unroll
    for (int rg = 0; rg < 4; rg++) {
      bf16x8 af = *(const bf16x8*)&base[(wr * 4 + rg) * 512 + lane * 8];
#pragma unroll
      for (int cg = 0; cg < 4; cg++)
        acc[rg][cg] = __builtin_amdgcn_mfma_f32_16x16x32_bf16(
            af, bfr[cg], acc[rg][cg], 0, 0, 0);
    }
    bcur++; if (bcur == 3) bcur = 0;
  }
#pragma unroll
  for (int cg = 0; cg < 4; cg++) {
    const int col = d0 + wc * 64 + cg * 16 + fr;
    const float bl = bias[col];
#pragma unroll
    for (int rg = 0; rg < 4; rg++)
#pragma unroll
      for (int r = 0; r < 4; r++)
        emb[(row0 + wr * 64 + rg * 16 + kg * 4 + r) * (size_t)D + col] =
            acc[rg][cg][r] + bl;
  }
}

// ---------------------------------------------------------------------------
__global__ __launch_bounds__(256) void norm_bf16_kernel(
    const float* __restrict__ in, ushort* __restrict__ outb, int nrows, int D) {
  int row = (int)((blockIdx.x * blockDim.x + threadIdx.x) >> 6);
  int lane = threadIdx.x & 63;
  if (row >= nrows) return;
  const float4* p = (const float4*)(in + (size_t)row * D);
  float4 v0 = p[lane];
  float4 v1 = p[lane + 64];
  float ss = v0.x * v0.x + v0.y * v0.y + v0.z * v0.z + v0.w * v0.w
           + v1.x * v1.x + v1.y * v1.y + v1.z * v1.z + v1.w * v1.w;
#pragma unroll
  for (int off = 32; off > 0; off >>= 1) ss += __shfl_xor(ss, off);
  float inv = 1.0f / fmaxf(sqrtf(ss), 1e-12f);
  ushort4 u0, u1;
  u0.x = f2bf(v0.x * inv); u0.y = f2bf(v0.y * inv);
  u0.z = f2bf(v0.z * inv); u0.w = f2bf(v0.w * inv);
  u1.x = f2bf(v1.x * inv); u1.y = f2bf(v1.y * inv);
  u1.z = f2bf(v1.z * inv); u1.w = f2bf(v1.w * inv);
  ushort* o = outb + (size_t)row * D;
  *(ushort4*)(o + 4 * lane) = u0;
  *(ushort4*)(o + 256 + 4 * lane) = u1;
}

// ---------------------------------------------------------------------------
// MFMA attention: phase 1 now 3-buffer counted-vmcnt (T4); phases 2/3
// (exp->bf16 swizzled P tile, P @ onehot MFMA) unchanged from r13.
// ---------------------------------------------------------------------------
#define STAGE_BODY(kt, pb)                                                    \
  {                                                                           \
    _Pragma("unroll")                                                         \
    for (int i_ = 0; i_ < 3; i_++) {                                          \
      const int seg_ = wave * 3 + i_;                                         \
      const ushort* src_ = (seg_ < 8)                                         \
          ? Qb + (q0 + seg_ * 16 + fr) * (size_t)D + (kt) * 32 + kg * 8       \
          : Sb + (s0 + (seg_ - 8) * 16 + fr) * (size_t)D + (kt) * 32 + kg * 8;\
      __builtin_amdgcn_global_load_lds(                                       \
          (const __attribute__((address_space(1))) void*)src_,                \
          (__attribute__((address_space(3))) void*)                           \
              &tile[(pb) * 12288 + seg_ * 512 + lane * 8],                    \
          16, 0, 0);                                                          \
    }                                                                         \
  }

__global__ __launch_bounds__(512, 4) void attn_mfma_kernel(
    const ushort* __restrict__ Qb, const ushort* __restrict__ Sb,
    const int* __restrict__ labels, float* __restrict__ partial,
    int nq, int D) {
  __shared__ ushort tile[3 * 12288];  // staging rotation; P[128][256] overlays [0,32768)
  __shared__ int lab[256];
  const int tid = threadIdx.x;
  const int wave = tid >> 6, lane = tid & 63;
  const int fr = lane & 15, kg = lane >> 4;
  const int wr = wave >> 2, wc = wave & 3;
  const long q0 = (long)blockIdx.x * 128;
  const int part = blockIdx.y;
  const long s0 = (long)part * 256;

  if (tid < 256) lab[tid] = labels[s0 + tid];

  f32x4 acc[4][4];
#pragma unroll
  for (int rg = 0; rg < 4; rg++)
#pragma unroll
    for (int cg = 0; cg < 4; cg++) acc[rg][cg] = (f32x4){0.f, 0.f, 0.f, 0.f};

  // ---- phase 1: score GEMM, 3-deep counted-vmcnt pipeline ----
  STAGE_BODY(0, 0)
  STAGE_BODY(1, 1)
  int bcur = 0;
  for (int t = 0; t < 16; t++) {
    if (t < 15) asm volatile("s_waitcnt vmcnt(3)" ::: "memory");  // stage(t) done
    else        asm volatile("s_waitcnt vmcnt(0)" ::: "memory");
    __builtin_amdgcn_sched_barrier(0);
    __builtin_amdgcn_s_barrier();
    if (t < 14) {
      int bnext = bcur + 2; if (bnext >= 3) bnext -= 3;
      STAGE_BODY(t + 2, bnext)
    }
    const ushort* base = &tile[bcur * 12288];
    bf16x8 bfr[4];
#pragma unroll
    for (int cg = 0; cg < 4; cg++)
      bfr[cg] = *(const bf16x8*)&base[(8 + wc * 4 + cg) * 512 + lane * 8];
#pragma unroll
    for (int rg = 0; rg < 4; rg++) {
      bf16x8 af = *(const bf16x8*)&base[(wr * 4 + rg) * 512 + lane * 8];
#pragma unroll
      for (int cg = 0; cg < 4; cg++)
        acc[rg][cg] = __builtin_amdgcn_mfma_f32_16x16x32_bf16(
            af, bfr[cg], acc[rg][cg], 0, 0, 0);
    }
    bcur++; if (bcur == 3) bcur = 0;
  }

  // ---- phase 2: P = exp(S) bf16 -> swizzled LDS ----
  __syncthreads();
#pragma unroll
  for (int rg = 0; rg < 4; rg++)
#pragma unroll
    for (int cg = 0; cg < 4; cg++)
#pragma unroll
      for (int r = 0; r < 4; r++) {
        const int q  = wr * 64 + rg * 16 + kg * 4 + r;
        const int sc = wc * 64 + cg * 16 + fr;
        const int byteoff = ((q << 9) + (sc << 1)) ^ ((q & 7) << 4);
        *(ushort*)((char*)tile + byteoff) = f2bf(__expf(acc[rg][cg][r]));
      }
  __syncthreads();

  // ---- phase 3: out = P @ onehot, K=256 (8 k-steps) ----
  f32x4 acc2[4];
#pragma unroll
  for (int rg = 0; rg < 4; rg++) acc2[rg] = (f32x4){0.f, 0.f, 0.f, 0.f};
  const int cls = wc * 16 + fr;
#pragma unroll
  for (int t = 0; t < 8; t++) {
    const int kb = t * 32 + kg * 8;
    int4 l0 = *(const int4*)&lab[kb];
    int4 l1 = *(const int4*)&lab[kb + 4];
    uint b0 = ((l0.x == cls) ? 0x3F80u : 0u) | (((l0.y == cls) ? 0x3F80u : 0u) << 16);
    uint b1 = ((l0.z == cls) ? 0x3F80u : 0u) | (((l0.w == cls) ? 0x3F80u : 0u) << 16);
    uint b2 = ((l1.x == cls) ? 0x3F80u : 0u) | (((l1.y == cls) ? 0x3F80u : 0u) << 16);
    uint b3 = ((l1.z == cls) ? 0x3F80u : 0u) | (((l1.w == cls) ? 0x3F80u : 0u) << 16);
    uint4 bu = {b0, b1, b2, b3};
    bf16x8 bfr = *(bf16x8*)&bu;
#pragma unroll
    for (int rg = 0; rg < 4; rg++) {
      const int qrow = wr * 64 + rg * 16 + fr;
      const int byteoff = ((qrow << 9) + (kb << 1)) ^ ((qrow & 7) << 4);
      bf16x8 af = *(const bf16x8*)((char*)tile + byteoff);
      acc2[rg] = __builtin_amdgcn_mfma_f32_16x16x32_bf16(af, bfr, acc2[rg], 0, 0, 0);
    }
  }
#pragma unroll
  for (int rg = 0; rg < 4; rg++)
#pragma unroll
    for (int r = 0; r < 4; r++) {
      const long q = q0 + wr * 64 + rg * 16 + kg * 4 + r;
      partial[((size_t)part * nq + q) * 64 + cls] = acc2[rg][r];
    }
}

// ---------------------------------------------------------------------------
__global__ __launch_bounds__(256) void combine_kernel(
    const float* __restrict__ partial, float* __restrict__ out, int nq, int nsplit) {
  int q = (int)((blockIdx.x * blockDim.x + threadIdx.x) >> 6);
  int lane = threadIdx.x & 63;
  if (q >= nq) return;
  float v = 0.0f;
  for (int h = 0; h < nsplit; h++)
    v += partial[((size_t)h * nq + q) * 64 + lane];
  float s = v;
#pragma unroll
  for (int off = 32; off > 0; off >>= 1) s += __shfl_xor(s, off);
  out[(size_t)q * 64 + lane] = v / s;
}

// ---------------------------------------------------------------------------
// Workspace: [0,8M) xb_s  [8M,24M) xb_q   (contiguous 12288x1024 bf16)
// [24M,25M) Wt  [25M,33M) s_emb  [33M,49M) q_emb (contiguous 12288x512 f32)
// after encode+norm: s_bf [0,4M), q_bf [4M,12M) (contiguous 12288x512 bf16),
// partial [12M,44M). All regions rewritten every call; aliases reuse only
// dead buffers; d_out fully overwritten by combine.
// ---------------------------------------------------------------------------
extern "C" void kernel_launch(void* const* d_in, const int* in_sizes, int n_in,
                              void* d_out, int out_size, void* d_ws, size_t ws_size,
                              hipStream_t stream) {
  const float* support = (const float*)d_in[0];
  const float* query   = (const float*)d_in[1];
  const float* W       = (const float*)d_in[2];
  const float* b       = (const float*)d_in[3];
  const int*   labels  = (const int*)d_in[4];

  const int d_dim    = in_sizes[3];            // 512
  const int in_dim   = in_sizes[2] / d_dim;    // 1024
  const int n_support = in_sizes[0] / in_dim;  // 4096
  const int n_query   = in_sizes[1] / in_dim;  // 8192
  const int n_all     = n_support + n_query;   // 12288

  char* base = (char*)d_ws;
  ushort* xb_s  = (ushort*)(base);                        // [0,8M) -- xb base
  ushort* xb_q  = (ushort*)(base + ((size_t)8 << 20));
  ushort* Wt    = (ushort*)(base + ((size_t)24 << 20));
  float*  s_emb = (float*)(base + ((size_t)25 << 20));    // emb base (24M B)
  float*  q_emb = (float*)(base + ((size_t)33 << 20));
  ushort* s_bf  = (ushort*)(base);                        // alias xb_s (dead)
  ushort* q_bf  = (ushort*)(base + ((size_t)4 << 20));    // alias xb (dead)
  float*  partial = (float*)(base + ((size_t)12 << 20));  // alias xb/Wt (dead)

  dim3 blk(256);
  cast_bf16_kernel<<<2048, blk, 0, stream>>>(support, xb_s, (size_t)n_support * in_dim / 4);
  cast_bf16_kernel<<<2048, blk, 0, stream>>>(query, xb_q, (size_t)n_query * in_dim / 4);
  transpose_cast_kernel<<<dim3(in_dim / 64, d_dim / 64), blk, 0, stream>>>(W, Wt, in_dim, d_dim);
  encode_mfma_kernel<<<dim3(n_all / 128, d_dim / 256), dim3(512), 0, stream>>>(
      xb_s, Wt, b, s_emb, in_dim, d_dim);
  norm_bf16_kernel<<<dim3(n_all / 4), blk, 0, stream>>>(s_emb, s_bf, n_all, d_dim);
  attn_mfma_kernel<<<dim3(n_query / 128, NPART), dim3(512), 0, stream>>>(
      q_bf, s_bf, labels, partial, n_query, d_dim);
  combine_kernel<<<dim3(n_query / 4), blk, 0, stream>>>(partial, (float*)d_out, n_query, NPART);
}